// Round 14
// baseline (1937.078 us; speedup 1.0000x reference)
//
#include <hip/hip_runtime.h>
#include <math.h>

// Problem constants (B,C,H,W = 8,256,64,64; N = H*W = 4096)
#define BQ 8
#define CQ 256
#define NQ 4096
#define MT 128            // m-tile per block -> 256 blocks, 1/CU
#define NSUP 64           // supersteps (2 chunks of 32n each)

typedef short s16x8 __attribute__((ext_vector_type(8)));
typedef short s16x4 __attribute__((ext_vector_type(4)));
typedef float f32x4 __attribute__((ext_vector_type(4)));
typedef unsigned int uint;

static __device__ __forceinline__ float4 ld4(const float* p) { return *(const float4*)p; }

static constexpr float LOG2E = 1.4426950408889634f;

static __device__ __forceinline__ short f2bf(float f) {
    return __builtin_bit_cast(short, (__bf16)f);
}
// monotonic uint key for float compare via atomicMax/Min
static __device__ __forceinline__ uint fkey(float f) {
    uint b = __builtin_bit_cast(uint, f);
    return b ^ (0x80000000u | (uint)((int)b >> 31));
}
static __device__ __forceinline__ float fdec(uint u) {
    uint b = (u & 0x80000000u) ? (u ^ 0x80000000u) : ~u;
    return __builtin_bit_cast(float, b);
}

// -------- K1: f' = (wq.x)*log2e, g = wk.x, xbf = bf16(x), fused batch max/min --------
__global__ void k_fg(const float* __restrict__ x, const float* __restrict__ wq,
                     const float* __restrict__ wk, float* __restrict__ fs,
                     float* __restrict__ g, short* __restrict__ xbf,
                     uint* __restrict__ fmxu, uint* __restrict__ fmnu) {
    int b = blockIdx.y;
    int t = threadIdx.x;
    int nl = (t & 31) * 2;
    int cg = t >> 5;                     // 0..7
    int n = blockIdx.x * 64 + nl;
    const float* xb = x + (size_t)b * CQ * NQ + n;
    uint* xo = (uint*)(xbf + (size_t)b * CQ * NQ + n);
    float f0 = 0.f, f1 = 0.f, g0 = 0.f, g1 = 0.f;
    int c0 = cg * 32;
#pragma unroll 8
    for (int c = c0; c < c0 + 32; ++c) {
        float2 v = *(const float2*)&xb[(size_t)c * NQ];
        f0 = fmaf(wq[c], v.x, f0);
        f1 = fmaf(wq[c], v.y, f1);
        g0 = fmaf(wk[c], v.x, g0);
        g1 = fmaf(wk[c], v.y, g1);
        uint p = (uint)(unsigned short)f2bf(v.x) | ((uint)(unsigned short)f2bf(v.y) << 16);
        xo[c * (NQ / 2)] = p;
    }
    __shared__ float sf[8][64], sg2[8][64];
    sf[cg][nl] = f0;  sf[cg][nl + 1] = f1;
    sg2[cg][nl] = g0; sg2[cg][nl + 1] = g1;
    __syncthreads();
    if (t < 64) {
        float f = 0.f, gg = 0.f;
#pragma unroll
        for (int i = 0; i < 8; ++i) { f += sf[i][t]; gg += sg2[i][t]; }
        f *= LOG2E;
        fs[b * NQ + blockIdx.x * 64 + t] = f;
        g[b * NQ + blockIdx.x * 64 + t]  = gg;
        float mx = f, mn = f;
#pragma unroll
        for (int off = 32; off; off >>= 1) {
            mx = fmaxf(mx, __shfl_xor(mx, off));
            mn = fminf(mn, __shfl_xor(mn, off));
        }
        if (t == 0) {
            atomicMax(&fmxu[b], fkey(mx));
            atomicMin(&fmnu[b], fkey(mn));
        }
    }
}

// LDS map (bytes):
//   [0, 64K)      : two 32KB pair-buffers (2 chunks of 256c x 32n bf16, q-swizzled)
//   [0, 128K)     : post-loop f32 partial-merge (8 pairs x 16KB)
//   [0, 64K)      : post-merge y_lds (128m x 512B, XOR-swizzled)
//   [128K, 144K)  : f_lds (4096 f32)
//   [144K, 146K)  : zbuf (512 f32)
#define FLDS_OFF 131072
#define ZBUF_OFF 147456
#define SMEM_BYTES 149504

// -------- K2 fused: y[c][m] = sum_n x[c][n] e[n,m];  o = (1-gam)*wv*(y/Z) + gam*x --------
// r7 structure (best measured: 99.6us) + T15 e-gen pipelining.
// 1024 thr, 16 waves (4/SIMD): ws = w&1 (chunk parity), wm = (w>>1)&3 (m-quarter),
// wc = w>>3 (c-half). Wave tile 128c x 32m (jc=8 x jm=2, acc 64 VGPR, 128-cap fits).
// T15: MFMA cluster consumes bvb[s&1] computed LAST superstep; e-gen for the next
// chunk runs after the MFMAs issue -> trans/VALU overlaps the matrix pipe.
__global__ void __launch_bounds__(1024, 4) k_attn(
    const short* __restrict__ xbf, const float* __restrict__ fsp,
    const float* __restrict__ gp, const uint* __restrict__ fmxu,
    const uint* __restrict__ fmnu, const float* __restrict__ wv,
    const float* __restrict__ x, const float* __restrict__ gamma,
    float* __restrict__ out) {
    __shared__ __align__(16) char smem[SMEM_BYTES];

    int bid = blockIdx.x;
    int b = bid & 7;            // batch -> XCD affinity (2MB xbf slice per XCD L2)
    int mblk = bid >> 3;        // 0..31
    int m0 = mblk * MT;
    int tid = threadIdx.x;
    int l = tid & 63;
    int w = tid >> 6;           // 0..15
    int ws = w & 1;             // chunk parity
    int wm = (w >> 1) & 3;      // m-quarter
    int wc = w >> 3;            // c-half
    int q = l >> 4;             // k-slot
    int cr = l & 15;            // A-row / B-col within frag
    int qp16 = (q ^ ((cr >> 1) & 3)) * 16;   // swizzled 16B slot for A-reads

    const short* xb = xbf + (size_t)b * CQ * NQ;
    const float* fb = fsp + b * NQ;

    // hoisted staging addresses: dest fixed per lane, src advances +64/superstep
    int dst0 = tid * 16;                 // chunk-half 0 (16KB)
    int dst1 = tid * 16 + 16384;         // chunk-half 1
    int srow = tid >> 2;                 // 0..255 (c row)
    int slq = (tid & 3) ^ ((srow >> 1) & 3);  // q-swizzle pre-applied on global src
    const short* src0 = xb + (size_t)srow * NQ + slq * 8;
    const short* src1 = src0 + 32;

    // ---- prolog: stage f (16KB) + pair 0 ----
    __builtin_amdgcn_global_load_lds(
        (const __attribute__((address_space(1))) void*)(fb + tid * 4),
        (__attribute__((address_space(3))) void*)(smem + FLDS_OFF + tid * 16), 16, 0, 0);
    __builtin_amdgcn_global_load_lds(
        (const __attribute__((address_space(1))) void*)src0,
        (__attribute__((address_space(3))) void*)(smem + dst0), 16, 0, 0);
    __builtin_amdgcn_global_load_lds(
        (const __attribute__((address_space(1))) void*)src1,
        (__attribute__((address_space(3))) void*)(smem + dst1), 16, 0, 0);
    src0 += 64;
    src1 += 64;

    float fmx = fdec(fmxu[b]), fmn = fdec(fmnu[b]);
    const float* gb = gp + b * NQ;
    float gj[2], nM[2], zac[2] = {0.f, 0.f};
#pragma unroll
    for (int jm = 0; jm < 2; ++jm) {
        float gv = gb[m0 + wm * 32 + jm * 16 + cr];
        gj[jm] = gv;
        nM[jm] = -((gv >= 0.f) ? gv * fmx : gv * fmn);
    }

    f32x4 acc[8][2];
#pragma unroll
    for (int jc = 0; jc < 8; ++jc)
#pragma unroll
        for (int jm = 0; jm < 2; ++jm) acc[jc][jm] = (f32x4){0.f, 0.f, 0.f, 0.f};

    __syncthreads();   // f + pair0 ready

    // ---- prologue e-gen: bv for chunk ws into bvb[0] ----
    const float* fl0 = (const float*)(smem + FLDS_OFF);
    s16x8 bvb[2][2];
    {
        const float* fls = fl0 + ws * 32;
        float4 fqa = *(const float4*)(fls + q * 8);
        float4 fqb = *(const float4*)(fls + q * 8 + 4);
        float fq[8] = {fqa.x, fqa.y, fqa.z, fqa.w, fqb.x, fqb.y, fqb.z, fqb.w};
#pragma unroll
        for (int jm = 0; jm < 2; ++jm) {
            float z = zac[jm];
#pragma unroll
            for (int i = 0; i < 8; ++i) {
                float e = __builtin_amdgcn_exp2f(fmaf(fq[i], gj[jm], nM[jm]));
                z += e;
                bvb[0][jm][i] = f2bf(e);
            }
            zac[jm] = z;
        }
    }

#pragma unroll 2
    for (int s = 0; s < NSUP; ++s) {
        if (s < NSUP - 1) {   // stage pair s+1 into buffer (s+1)&1
            char* nbuf = smem + ((s + 1) & 1) * 32768;
            __builtin_amdgcn_global_load_lds(
                (const __attribute__((address_space(1))) void*)src0,
                (__attribute__((address_space(3))) void*)(nbuf + dst0), 16, 0, 0);
            __builtin_amdgcn_global_load_lds(
                (const __attribute__((address_space(1))) void*)src1,
                (__attribute__((address_space(3))) void*)(nbuf + dst1), 16, 0, 0);
            src0 += 64;
            src1 += 64;
        }
        // ---- MFMA cluster FIRST: chunk 2s+ws, bv precomputed last superstep ----
        const char* cbuf = smem + (s & 1) * 32768 + ws * 16384;
#pragma unroll
        for (int jc = 0; jc < 8; ++jc) {
            s16x8 av = *(const s16x8*)(cbuf + (wc * 128 + jc * 16 + cr) * 64 + qp16);
            acc[jc][0] = __builtin_amdgcn_mfma_f32_16x16x32_bf16(av, bvb[s & 1][0], acc[jc][0], 0, 0, 0);
            acc[jc][1] = __builtin_amdgcn_mfma_f32_16x16x32_bf16(av, bvb[s & 1][1], acc[jc][1], 0, 0, 0);
        }
        // ---- e-gen for chunk 2(s+1)+ws: trans/VALU overlaps the matrix pipe ----
        if (s < NSUP - 1) {
            const float* fls = fl0 + (2 * (s + 1) + ws) * 32;
            float4 fqa = *(const float4*)(fls + q * 8);
            float4 fqb = *(const float4*)(fls + q * 8 + 4);
            float fq[8] = {fqa.x, fqa.y, fqa.z, fqa.w, fqb.x, fqb.y, fqb.z, fqb.w};
#pragma unroll
            for (int jm = 0; jm < 2; ++jm) {
                float z = zac[jm];
#pragma unroll
                for (int i = 0; i < 8; ++i) {
                    float e = __builtin_amdgcn_exp2f(fmaf(fq[i], gj[jm], nM[jm]));
                    z += e;
                    bvb[(s + 1) & 1][jm][i] = f2bf(e);
                }
                zac[jm] = z;
            }
        }
        __syncthreads();   // pair s+1 landed; everyone done with buf (s&1)
    }

    // ---- Z: butterfly over k-slots, then exchange across ws-partner ----
    float zf[2];
#pragma unroll
    for (int jm = 0; jm < 2; ++jm) {
        float z = zac[jm];
        z += __shfl_xor(z, 16);
        z += __shfl_xor(z, 32);
        zf[jm] = z;
    }
    float* zb = (float*)(smem + ZBUF_OFF);
    if (q == 0) {
#pragma unroll
        for (int jm = 0; jm < 2; ++jm) zb[w * 32 + jm * 16 + cr] = zf[jm];
    }
    __syncthreads();
#pragma unroll
    for (int jm = 0; jm < 2; ++jm) zf[jm] += zb[(w ^ 1) * 32 + jm * 16 + cr];

    // ---- acc merge across ws pairs: ws1 -> LDS (f32, 8 x 16KB), ws0 adds ----
    {
        int p = wc * 4 + wm;
        float* mrg = (float*)(smem + p * 16384);
        if (ws == 1) {
#pragma unroll
            for (int jc = 0; jc < 8; ++jc)
#pragma unroll
                for (int jm = 0; jm < 2; ++jm)
                    *(f32x4*)(mrg + ((jc * 2 + jm) * 64 + l) * 4) = acc[jc][jm];
        }
        __syncthreads();
        if (ws == 0) {
#pragma unroll
            for (int jc = 0; jc < 8; ++jc)
#pragma unroll
                for (int jm = 0; jm < 2; ++jm) {
                    f32x4 o = *(const f32x4*)(mrg + ((jc * 2 + jm) * 64 + l) * 4);
                    acc[jc][jm] += o;
                }
        }
        __syncthreads();
    }

    // ---- y_norm -> LDS (ws0 waves): y_lds[m][c] bf16, 512B rows, XOR-swizzled ----
    if (ws == 0) {
        float rzl[2];
#pragma unroll
        for (int jm = 0; jm < 2; ++jm) rzl[jm] = 1.0f / zf[jm];
#pragma unroll
        for (int jc = 0; jc < 8; ++jc) {
#pragma unroll
            for (int jm = 0; jm < 2; ++jm) {
                int mloc = wm * 32 + jm * 16 + cr;
                int cb = (wc * 256 + jc * 32 + q * 8) ^ ((mloc & 7) << 4);
                s16x4 v;
#pragma unroll
                for (int r = 0; r < 4; ++r) v[r] = f2bf(acc[jc][jm][r] * rzl[jm]);
                *(s16x4*)(smem + mloc * 512 + cb) = v;
            }
        }
    }
    __syncthreads();

    // ---- GEMM2: o[c_out][m] = wv[c_out][:] . y_norm[:][m], K=256 (16 waves) ----
    int co0 = w * 16;
    f32x4 acc2[8];
#pragma unroll
    for (int jm2 = 0; jm2 < 8; ++jm2) acc2[jm2] = (f32x4){0.f, 0.f, 0.f, 0.f};

#pragma unroll 2
    for (int ks = 0; ks < 8; ++ks) {
        s16x8 a2;
        {
            const float* wr = wv + (size_t)(co0 + cr) * CQ + ks * 32 + q * 8;
            float4 wa = ld4(wr);
            float4 wb = ld4(wr + 4);
            a2[0] = f2bf(wa.x); a2[1] = f2bf(wa.y);
            a2[2] = f2bf(wa.z); a2[3] = f2bf(wa.w);
            a2[4] = f2bf(wb.x); a2[5] = f2bf(wb.y);
            a2[6] = f2bf(wb.z); a2[7] = f2bf(wb.w);
        }
#pragma unroll
        for (int jm2 = 0; jm2 < 8; ++jm2) {
            int mloc = jm2 * 16 + cr;
            s16x8 b2 = *(const s16x8*)(smem + mloc * 512 + ((ks * 64 + q * 16) ^ ((mloc & 7) << 4)));
            acc2[jm2] = __builtin_amdgcn_mfma_f32_16x16x32_bf16(a2, b2, acc2[jm2], 0, 0, 0);
        }
    }

    // ---- epilogue ----
    float gam = gamma[0];
    float omg = 1.f - gam;
    if (gam != 0.f) {
#pragma unroll
        for (int jm2 = 0; jm2 < 8; ++jm2)
#pragma unroll
            for (int r = 0; r < 4; ++r) {
                int c_out = co0 + q * 4 + r;
                size_t idx = ((size_t)b * CQ + c_out) * NQ + m0 + jm2 * 16 + cr;
                __builtin_nontemporal_store(
                    fmaf(gam, x[idx], acc2[jm2][r] * omg), out + idx);
            }
    } else {
#pragma unroll
        for (int jm2 = 0; jm2 < 8; ++jm2)
#pragma unroll
            for (int r = 0; r < 4; ++r) {
                int c_out = co0 + q * 4 + r;
                size_t idx = ((size_t)b * CQ + c_out) * NQ + m0 + jm2 * 16 + cr;
                __builtin_nontemporal_store(acc2[jm2][r] * omg, out + idx);
            }
    }
}

extern "C" void kernel_launch(void* const* d_in, const int* in_sizes, int n_in,
                              void* d_out, int out_size, void* d_ws, size_t ws_size,
                              hipStream_t stream) {
    const float* x     = (const float*)d_in[0];
    const float* wq    = (const float*)d_in[1];
    const float* wk    = (const float*)d_in[2];
    const float* wv    = (const float*)d_in[3];
    const float* gamma = (const float*)d_in[4];
    float* out = (float*)d_out;

    // ws (floats): fs[B*N] | g[B*N] | fmxu[8]+fmnu[8] (uint) | pad -> xbf (bf16) [B*C*N]
    float* ws  = (float*)d_ws;
    float* fs  = ws;
    float* g   = ws + BQ * NQ;
    uint* fmxu = (uint*)(ws + 2 * BQ * NQ);
    uint* fmnu = fmxu + 8;
    short* xbf = (short*)(ws + 2 * BQ * NQ + 64);

    hipMemsetAsync(fmxu, 0x00, 32, stream);   // lowest key
    hipMemsetAsync(fmnu, 0xFF, 32, stream);   // highest key
    hipLaunchKernelGGL(k_fg, dim3(NQ / 64, BQ), dim3(256), 0, stream,
                       x, wq, wk, fs, g, xbf, fmxu, fmnu);
    hipLaunchKernelGGL(k_attn, dim3(BQ * (NQ / MT)), dim3(1024), 0, stream,
                       xbf, fs, g, fmxu, fmnu, wv, x, gamma, out);
}

// Round 15
// 121.952 us; speedup vs baseline: 15.8839x; 15.8839x over previous
//
#include <hip/hip_runtime.h>
#include <math.h>

// Problem constants (B,C,H,W = 8,256,64,64; N = H*W = 4096)
#define BQ 8
#define CQ 256
#define NQ 4096
#define MT 128            // m-tile per block -> 256 blocks, 1/CU
#define NSUP 64           // supersteps (2 chunks of 32n each), even

typedef short s16x8 __attribute__((ext_vector_type(8)));
typedef short s16x4 __attribute__((ext_vector_type(4)));
typedef float f32x4 __attribute__((ext_vector_type(4)));
typedef unsigned int uint;

static __device__ __forceinline__ float4 ld4(const float* p) { return *(const float4*)p; }

static constexpr float LOG2E = 1.4426950408889634f;

static __device__ __forceinline__ short f2bf(float f) {
    return __builtin_bit_cast(short, (__bf16)f);
}
// monotonic uint key for float compare via atomicMax/Min
static __device__ __forceinline__ uint fkey(float f) {
    uint b = __builtin_bit_cast(uint, f);
    return b ^ (0x80000000u | (uint)((int)b >> 31));
}
static __device__ __forceinline__ float fdec(uint u) {
    uint b = (u & 0x80000000u) ? (u ^ 0x80000000u) : ~u;
    return __builtin_bit_cast(float, b);
}

// -------- K1: f' = (wq.x)*log2e, g = wk.x, xbf = bf16(x), fused batch max/min --------
__global__ void k_fg(const float* __restrict__ x, const float* __restrict__ wq,
                     const float* __restrict__ wk, float* __restrict__ fs,
                     float* __restrict__ g, short* __restrict__ xbf,
                     uint* __restrict__ fmxu, uint* __restrict__ fmnu) {
    int b = blockIdx.y;
    int t = threadIdx.x;
    int nl = (t & 31) * 2;
    int cg = t >> 5;                     // 0..7
    int n = blockIdx.x * 64 + nl;
    const float* xb = x + (size_t)b * CQ * NQ + n;
    uint* xo = (uint*)(xbf + (size_t)b * CQ * NQ + n);
    float f0 = 0.f, f1 = 0.f, g0 = 0.f, g1 = 0.f;
    int c0 = cg * 32;
#pragma unroll 8
    for (int c = c0; c < c0 + 32; ++c) {
        float2 v = *(const float2*)&xb[(size_t)c * NQ];
        f0 = fmaf(wq[c], v.x, f0);
        f1 = fmaf(wq[c], v.y, f1);
        g0 = fmaf(wk[c], v.x, g0);
        g1 = fmaf(wk[c], v.y, g1);
        uint p = (uint)(unsigned short)f2bf(v.x) | ((uint)(unsigned short)f2bf(v.y) << 16);
        xo[c * (NQ / 2)] = p;
    }
    __shared__ float sf[8][64], sg2[8][64];
    sf[cg][nl] = f0;  sf[cg][nl + 1] = f1;
    sg2[cg][nl] = g0; sg2[cg][nl + 1] = g1;
    __syncthreads();
    if (t < 64) {
        float f = 0.f, gg = 0.f;
#pragma unroll
        for (int i = 0; i < 8; ++i) { f += sf[i][t]; gg += sg2[i][t]; }
        f *= LOG2E;
        fs[b * NQ + blockIdx.x * 64 + t] = f;
        g[b * NQ + blockIdx.x * 64 + t]  = gg;
        float mx = f, mn = f;
#pragma unroll
        for (int off = 32; off; off >>= 1) {
            mx = fmaxf(mx, __shfl_xor(mx, off));
            mn = fminf(mn, __shfl_xor(mn, off));
        }
        if (t == 0) {
            atomicMax(&fmxu[b], fkey(mx));
            atomicMin(&fmnu[b], fkey(mn));
        }
    }
}

// LDS map (bytes):
//   [0, 64K)      : two 32KB pair-buffers (2 chunks of 256c x 32n bf16, q-swizzled)
//   [0, 128K)     : post-loop f32 partial-merge (8 pairs x 16KB)
//   [0, 64K)      : post-merge y_lds (128m x 512B, XOR-swizzled)
//   [128K, 144K)  : f_lds (4096 f32)
//   [144K, 146K)  : zbuf (512 f32)
#define FLDS_OFF 131072
#define ZBUF_OFF 147456
#define SMEM_BYTES 149504

#define GSRC(p) (const __attribute__((address_space(1))) void*)(p)
#define LDST(p) (__attribute__((address_space(3))) void*)(p)

// -------- K2 fused: y[c][m] = sum_n x[c][n] e[n,m];  o = (1-gam)*wv*(y/Z) + gam*x --------
// r7 structure (best measured: 99.6us) + T15 e-gen pipelining with EXPLICIT
// ping-pong (named bvA/bvB — no runtime-indexed arrays; rule-#20-safe).
// 1024 thr, 16 waves (4/SIMD): ws = w&1, wm = (w>>1)&3, wc = w>>3.
// Wave tile 128c x 32m (jc=8 x jm=2). MFMA consumes the bv computed LAST
// superstep; e-gen of the NEXT chunk overlaps the matrix pipe.
__global__ void __launch_bounds__(1024, 4) k_attn(
    const short* __restrict__ xbf, const float* __restrict__ fsp,
    const float* __restrict__ gp, const uint* __restrict__ fmxu,
    const uint* __restrict__ fmnu, const float* __restrict__ wv,
    const float* __restrict__ x, const float* __restrict__ gamma,
    float* __restrict__ out) {
    __shared__ __align__(16) char smem[SMEM_BYTES];

    int bid = blockIdx.x;
    int b = bid & 7;            // batch -> XCD affinity (2MB xbf slice per XCD L2)
    int mblk = bid >> 3;        // 0..31
    int m0 = mblk * MT;
    int tid = threadIdx.x;
    int l = tid & 63;
    int w = tid >> 6;           // 0..15
    int ws = w & 1;             // chunk parity
    int wm = (w >> 1) & 3;      // m-quarter
    int wc = w >> 3;            // c-half
    int q = l >> 4;             // k-slot
    int cr = l & 15;            // A-row / B-col within frag
    int qp16 = (q ^ ((cr >> 1) & 3)) * 16;   // swizzled 16B slot for A-reads

    const short* xb = xbf + (size_t)b * CQ * NQ;
    const float* fb = fsp + b * NQ;

    // hoisted staging addresses: dest fixed per lane, src advances +64/superstep
    int dst0 = tid * 16;                 // chunk-half 0 (16KB)
    int dst1 = tid * 16 + 16384;         // chunk-half 1
    int srow = tid >> 2;                 // 0..255 (c row)
    int slq = (tid & 3) ^ ((srow >> 1) & 3);  // q-swizzle pre-applied on global src
    const short* src0 = xb + (size_t)srow * NQ + slq * 8;
    const short* src1 = src0 + 32;

    // ---- prolog: stage f (16KB) + pair 0 ----
    __builtin_amdgcn_global_load_lds(GSRC(fb + tid * 4),
        LDST(smem + FLDS_OFF + tid * 16), 16, 0, 0);
    __builtin_amdgcn_global_load_lds(GSRC(src0), LDST(smem + dst0), 16, 0, 0);
    __builtin_amdgcn_global_load_lds(GSRC(src1), LDST(smem + dst1), 16, 0, 0);
    src0 += 64;
    src1 += 64;

    float fmx = fdec(fmxu[b]), fmn = fdec(fmnu[b]);
    const float* gb = gp + b * NQ;
    float gj0, gj1, nM0, nM1;
    {
        float gv0 = gb[m0 + wm * 32 + cr];
        float gv1 = gb[m0 + wm * 32 + 16 + cr];
        gj0 = gv0; gj1 = gv1;
        nM0 = -((gv0 >= 0.f) ? gv0 * fmx : gv0 * fmn);
        nM1 = -((gv1 >= 0.f) ? gv1 * fmx : gv1 * fmn);
    }
    float zac0 = 0.f, zac1 = 0.f;

    f32x4 acc[8][2];
#pragma unroll
    for (int jc = 0; jc < 8; ++jc)
#pragma unroll
        for (int jm = 0; jm < 2; ++jm) acc[jc][jm] = (f32x4){0.f, 0.f, 0.f, 0.f};

    __syncthreads();   // f + pair0 ready

    const float* fl0 = (const float*)(smem + FLDS_OFF);

    // e-gen macro: chunk index -> named dst frags (all operands named, no arrays)
#define EGEN(CHUNK, DV0, DV1)                                                      \
    {                                                                              \
        const float* fls_ = fl0 + (CHUNK) * 32;                                    \
        float4 fa_ = *(const float4*)(fls_ + q * 8);                               \
        float4 fb_ = *(const float4*)(fls_ + q * 8 + 4);                           \
        float fq_[8] = {fa_.x, fa_.y, fa_.z, fa_.w, fb_.x, fb_.y, fb_.z, fb_.w};   \
        float z0_ = zac0, z1_ = zac1;                                              \
        _Pragma("unroll")                                                          \
        for (int i_ = 0; i_ < 8; ++i_) {                                           \
            float e0_ = __builtin_amdgcn_exp2f(fmaf(fq_[i_], gj0, nM0));           \
            float e1_ = __builtin_amdgcn_exp2f(fmaf(fq_[i_], gj1, nM1));           \
            z0_ += e0_; z1_ += e1_;                                                \
            DV0[i_] = f2bf(e0_); DV1[i_] = f2bf(e1_);                              \
        }                                                                          \
        zac0 = z0_; zac1 = z1_;                                                    \
    }

#define MFMA8(CBUF, BV0, BV1)                                                      \
    {                                                                              \
        _Pragma("unroll")                                                          \
        for (int jc_ = 0; jc_ < 8; ++jc_) {                                        \
            s16x8 av_ = *(const s16x8*)((CBUF) + (wc * 128 + jc_ * 16 + cr) * 64 + qp16); \
            acc[jc_][0] = __builtin_amdgcn_mfma_f32_16x16x32_bf16(av_, BV0, acc[jc_][0], 0, 0, 0); \
            acc[jc_][1] = __builtin_amdgcn_mfma_f32_16x16x32_bf16(av_, BV1, acc[jc_][1], 0, 0, 0); \
        }                                                                          \
    }

#define STAGEPAIR(BUFOFF)                                                          \
    {                                                                              \
        __builtin_amdgcn_global_load_lds(GSRC(src0), LDST(smem + (BUFOFF) + dst0), 16, 0, 0); \
        __builtin_amdgcn_global_load_lds(GSRC(src1), LDST(smem + (BUFOFF) + dst1), 16, 0, 0); \
        src0 += 64;                                                                \
        src1 += 64;                                                                \
    }

    // prologue e-gen: bvA <- chunk ws
    s16x8 bvA0, bvA1, bvB0, bvB1;
    EGEN(ws, bvA0, bvA1)

    for (int s = 0; s < NSUP; s += 2) {
        // ---- superstep A (even s; reads buf0): stage pair s+1 -> buf1 ----
        STAGEPAIR(32768)
        MFMA8(smem + ws * 16384, bvA0, bvA1)
        EGEN(2 * (s + 1) + ws, bvB0, bvB1)        // overlaps matrix pipe
        __syncthreads();   // pair s+1 landed; buf0 free

        // ---- superstep B (s+1; reads buf1): stage pair s+2 -> buf0 ----
        if (s + 2 < NSUP) STAGEPAIR(0)
        MFMA8(smem + 32768 + ws * 16384, bvB0, bvB1)
        if (s + 2 < NSUP) EGEN(2 * (s + 2) + ws, bvA0, bvA1)
        __syncthreads();   // pair s+2 landed; buf1 free
    }

    // ---- Z: butterfly over k-slots, then exchange across ws-partner ----
    float zf0 = zac0, zf1 = zac1;
    zf0 += __shfl_xor(zf0, 16); zf0 += __shfl_xor(zf0, 32);
    zf1 += __shfl_xor(zf1, 16); zf1 += __shfl_xor(zf1, 32);
    float* zb = (float*)(smem + ZBUF_OFF);
    if (q == 0) {
        zb[w * 32 + cr] = zf0;
        zb[w * 32 + 16 + cr] = zf1;
    }
    __syncthreads();
    zf0 += zb[(w ^ 1) * 32 + cr];
    zf1 += zb[(w ^ 1) * 32 + 16 + cr];

    // ---- acc merge across ws pairs: ws1 -> LDS (f32, 8 x 16KB), ws0 adds ----
    {
        int p = wc * 4 + wm;
        float* mrg = (float*)(smem + p * 16384);
        if (ws == 1) {
#pragma unroll
            for (int jc = 0; jc < 8; ++jc)
#pragma unroll
                for (int jm = 0; jm < 2; ++jm)
                    *(f32x4*)(mrg + ((jc * 2 + jm) * 64 + l) * 4) = acc[jc][jm];
        }
        __syncthreads();
        if (ws == 0) {
#pragma unroll
            for (int jc = 0; jc < 8; ++jc)
#pragma unroll
                for (int jm = 0; jm < 2; ++jm) {
                    f32x4 o = *(const f32x4*)(mrg + ((jc * 2 + jm) * 64 + l) * 4);
                    acc[jc][jm] += o;
                }
        }
        __syncthreads();
    }

    // ---- y_norm -> LDS (ws0 waves): y_lds[m][c] bf16, 512B rows, XOR-swizzled ----
    if (ws == 0) {
        float rz0 = 1.0f / zf0, rz1 = 1.0f / zf1;
#pragma unroll
        for (int jc = 0; jc < 8; ++jc) {
            {
                int mloc = wm * 32 + cr;
                int cb = (wc * 256 + jc * 32 + q * 8) ^ ((mloc & 7) << 4);
                s16x4 v;
#pragma unroll
                for (int r = 0; r < 4; ++r) v[r] = f2bf(acc[jc][0][r] * rz0);
                *(s16x4*)(smem + mloc * 512 + cb) = v;
            }
            {
                int mloc = wm * 32 + 16 + cr;
                int cb = (wc * 256 + jc * 32 + q * 8) ^ ((mloc & 7) << 4);
                s16x4 v;
#pragma unroll
                for (int r = 0; r < 4; ++r) v[r] = f2bf(acc[jc][1][r] * rz1);
                *(s16x4*)(smem + mloc * 512 + cb) = v;
            }
        }
    }
    __syncthreads();

    // ---- GEMM2: o[c_out][m] = wv[c_out][:] . y_norm[:][m], K=256 (16 waves) ----
    int co0 = w * 16;
    f32x4 acc2[8];
#pragma unroll
    for (int jm2 = 0; jm2 < 8; ++jm2) acc2[jm2] = (f32x4){0.f, 0.f, 0.f, 0.f};

#pragma unroll 2
    for (int ks = 0; ks < 8; ++ks) {
        s16x8 a2;
        {
            const float* wr = wv + (size_t)(co0 + cr) * CQ + ks * 32 + q * 8;
            float4 wa = ld4(wr);
            float4 wb = ld4(wr + 4);
            a2[0] = f2bf(wa.x); a2[1] = f2bf(wa.y);
            a2[2] = f2bf(wa.z); a2[3] = f2bf(wa.w);
            a2[4] = f2bf(wb.x); a2[5] = f2bf(wb.y);
            a2[6] = f2bf(wb.z); a2[7] = f2bf(wb.w);
        }
#pragma unroll
        for (int jm2 = 0; jm2 < 8; ++jm2) {
            int mloc = jm2 * 16 + cr;
            s16x8 b2 = *(const s16x8*)(smem + mloc * 512 + ((ks * 64 + q * 16) ^ ((mloc & 7) << 4)));
            acc2[jm2] = __builtin_amdgcn_mfma_f32_16x16x32_bf16(a2, b2, acc2[jm2], 0, 0, 0);
        }
    }

    // ---- epilogue ----
    float gam = gamma[0];
    float omg = 1.f - gam;
    if (gam != 0.f) {
#pragma unroll
        for (int jm2 = 0; jm2 < 8; ++jm2)
#pragma unroll
            for (int r = 0; r < 4; ++r) {
                int c_out = co0 + q * 4 + r;
                size_t idx = ((size_t)b * CQ + c_out) * NQ + m0 + jm2 * 16 + cr;
                __builtin_nontemporal_store(
                    fmaf(gam, x[idx], acc2[jm2][r] * omg), out + idx);
            }
    } else {
#pragma unroll
        for (int jm2 = 0; jm2 < 8; ++jm2)
#pragma unroll
            for (int r = 0; r < 4; ++r) {
                int c_out = co0 + q * 4 + r;
                size_t idx = ((size_t)b * CQ + c_out) * NQ + m0 + jm2 * 16 + cr;
                __builtin_nontemporal_store(acc2[jm2][r] * omg, out + idx);
            }
    }
}

extern "C" void kernel_launch(void* const* d_in, const int* in_sizes, int n_in,
                              void* d_out, int out_size, void* d_ws, size_t ws_size,
                              hipStream_t stream) {
    const float* x     = (const float*)d_in[0];
    const float* wq    = (const float*)d_in[1];
    const float* wk    = (const float*)d_in[2];
    const float* wv    = (const float*)d_in[3];
    const float* gamma = (const float*)d_in[4];
    float* out = (float*)d_out;

    // ws (floats): fs[B*N] | g[B*N] | fmxu[8]+fmnu[8] (uint) | pad -> xbf (bf16) [B*C*N]
    float* ws  = (float*)d_ws;
    float* fs  = ws;
    float* g   = ws + BQ * NQ;
    uint* fmxu = (uint*)(ws + 2 * BQ * NQ);
    uint* fmnu = fmxu + 8;
    short* xbf = (short*)(ws + 2 * BQ * NQ + 64);

    hipMemsetAsync(fmxu, 0x00, 32, stream);   // lowest key
    hipMemsetAsync(fmnu, 0xFF, 32, stream);   // highest key
    hipLaunchKernelGGL(k_fg, dim3(NQ / 64, BQ), dim3(256), 0, stream,
                       x, wq, wk, fs, g, xbf, fmxu, fmnu);
    hipLaunchKernelGGL(k_attn, dim3(BQ * (NQ / MT)), dim3(1024), 0, stream,
                       xbf, fs, g, fmxu, fmnu, wv, x, gamma, out);
}